// Round 7
// baseline (414.474 us; speedup 1.0000x reference)
//
#include <hip/hip_runtime.h>
#include <stdint.h>

#define TOKENS 32
#define IN_DIM 8192
#define OUT_DIM 8192
#define NWAVE 8                       // K-split waves per block
#define BK 64                         // int32 elements per chunk
#define KRANGE (IN_DIM / NWAVE)       // 1024 k per wave
#define NCHUNK (KRANGE / BK)          // 16 chunks (even)

typedef __bf16 bf16x8 __attribute__((ext_vector_type(8)));
typedef float f32x16 __attribute__((ext_vector_type(16)));

// pack truncate-to-bf16 of two fp32 into one dword (lo=f0, hi=f1).
// Exact for integer-valued fp32 |v|<=255 (the weights); truncation for A.
static __device__ __forceinline__ uint32_t pk_bf16_2(float f0, float f1) {
    return __builtin_amdgcn_perm(__float_as_uint(f1), __float_as_uint(f0), 0x07060302u);
}
static __device__ __forceinline__ float trunc_bf(float f) {
    return __uint_as_float(__float_as_uint(f) & 0xffff0000u);
}

// out[t,o] = scale[o] * ( sum_k A~[t,k]*q[o,k] - zp[o]*sum_k A~[t,k] ) + bias[o]
// A~ = bf16-truncated input (rowsum uses the SAME truncated values -> zp exact).
// W arrives int32 (harness sign-extends int8 -> const int*): 256 MB streamed once.
// 256 blocks x 8 waves; each wave K-splits with a PRIVATE double-buffered LDS
// panel (no barriers in main loop), counted vmcnt keeps next chunk in flight.
__global__ __launch_bounds__(512, 2) void gemm_kernel(
        const float* __restrict__ in,
        const int* __restrict__ w,
        const int* __restrict__ zp,
        const float* __restrict__ scale,
        const float* __restrict__ bias,
        float* __restrict__ out) {
    // per-wave private double buffer: [wave][buf][row][BK] int32 = 128 KB
    __shared__ int lds[NWAVE][2][32][BK];

    const int tid   = threadIdx.x;
    const int wv    = tid >> 6;       // 0..7 : K-split index
    const int lane  = tid & 63;
    const int lo    = lane & 31;      // A-row (token) / B-row (output)
    const int hi    = lane >> 5;      // k sub-chunk
    const int obase = blockIdx.x * 32;
    const int k0    = wv * KRANGE;

    // Swizzle: LDS[r][d] = W[obase+r][chunk + (d ^ ((r&7)<<2))] (dwords).
    // global_load_lds writes LDS linearly (base + lane*16); the XOR is applied
    // to the per-lane GLOBAL source address (both-sides-or-neither rule).
    auto stage = [&](int c, int b) {
#pragma unroll
        for (int p = 0; p < 8; ++p) {
            const int r   = p * 4 + (lane >> 4);        // 4 rows per gll
            const int swr = (r & 7) << 2;
            const int* g = w + (size_t)(obase + r) * IN_DIM + k0 + c * BK
                             + (((lane & 15) * 4) ^ swr);
            __builtin_amdgcn_global_load_lds(
                (const __attribute__((address_space(1))) void*)g,
                (__attribute__((address_space(3))) void*)&lds[wv][b][p * 4][0],
                16, 0, 0);
        }
    };

    const float* ain = in + (size_t)lo * IN_DIM + k0 + hi * 8;
    auto aload = [&](int c, float4 (&ab)[8]) {
#pragma unroll
        for (int j = 0; j < 8; ++j)
            ab[j] = *reinterpret_cast<const float4*>(ain + c * BK + (j >> 1) * 16 + (j & 1) * 4);
    };

    f32x16 acc;
#pragma unroll
    for (int i = 0; i < 16; ++i) acc[i] = 0.f;
    float rs = 0.f;                                     // truncated-A partial rowsum

    const int sw = (lo & 7) << 2;
    const int* lrow0 = &lds[wv][0][lo][0];
    const int* lrow1 = &lds[wv][1][lo][0];

    auto compute = [&](const int* lrow, const float4 (&ab)[8]) {
#pragma unroll
        for (int s = 0; s < 4; ++s) {
            const int d0 = s * 16 + hi * 8;
            const float4 a0 = ab[2 * s];
            const float4 a1 = ab[2 * s + 1];
            int4 b0 = *reinterpret_cast<const int4*>(lrow + (d0 ^ sw));
            int4 b1 = *reinterpret_cast<const int4*>(lrow + ((d0 + 4) ^ sw));

            rs += trunc_bf(a0.x) + trunc_bf(a0.y) + trunc_bf(a0.z) + trunc_bf(a0.w)
                + trunc_bf(a1.x) + trunc_bf(a1.y) + trunc_bf(a1.z) + trunc_bf(a1.w);

            union { uint32_t u[4]; bf16x8 v; } af, bf_;
            af.u[0] = pk_bf16_2(a0.x, a0.y);
            af.u[1] = pk_bf16_2(a0.z, a0.w);
            af.u[2] = pk_bf16_2(a1.x, a1.y);
            af.u[3] = pk_bf16_2(a1.z, a1.w);
            bf_.u[0] = pk_bf16_2((float)b0.x, (float)b0.y);
            bf_.u[1] = pk_bf16_2((float)b0.z, (float)b0.w);
            bf_.u[2] = pk_bf16_2((float)b1.x, (float)b1.y);
            bf_.u[3] = pk_bf16_2((float)b1.z, (float)b1.w);

            acc = __builtin_amdgcn_mfma_f32_32x32x16_bf16(af.v, bf_.v, acc, 0, 0, 0);
        }
    };

    float4 ab0[8], ab1[8];

    // Queue order per chunk: [gll_c x8, A_c x8]; vmcnt(16) at the top of
    // compute(c) retires exactly chunk c's 16 ops while chunk c+1's 16 ops
    // (8 KB W + 8 KB A per wave) stay in flight under the compute.
    stage(0, 0);
    aload(0, ab0);
    for (int cc = 0; cc < NCHUNK; cc += 2) {
        stage(cc + 1, 1);
        aload(cc + 1, ab1);
        asm volatile("s_waitcnt vmcnt(16)" ::: "memory");
        compute(lrow0, ab0);

        if (cc + 2 < NCHUNK) {
            stage(cc + 2, 0);
            aload(cc + 2, ab0);
            asm volatile("s_waitcnt vmcnt(16)" ::: "memory");
        } else {
            asm volatile("s_waitcnt vmcnt(0)" ::: "memory");
        }
        compute(lrow1, ab1);
    }

    // ---- cross-wave reduce (overlay LDS) + fused epilogue ----
    rs += __shfl_down(rs, 32);                          // lanes 0..31: per-token partial
    __syncthreads();                                    // all waves done with bufs
    float* red = (float*)&lds[0][0][0][0];              // [NWAVE][1024]
    float* rsl = red + NWAVE * TOKENS * 32;             // [NWAVE][32]
#pragma unroll
    for (int r = 0; r < 16; ++r) {
        const int m = (r & 3) + 8 * (r >> 2) + 4 * hi;  // token (validated layout)
        red[wv * (TOKENS * 32) + m * 32 + lo] = acc[r];
    }
    if (lane < 32) rsl[wv * 32 + lane] = rs;
    __syncthreads();

    for (int idx = tid; idx < TOKENS * 32; idx += 512) {
        const int m = idx >> 5;
        const int o = obase + (idx & 31);
        float s = 0.f, rsum = 0.f;
#pragma unroll
        for (int wvi = 0; wvi < NWAVE; ++wvi) {
            s    += red[wvi * (TOKENS * 32) + idx];
            rsum += rsl[wvi * 32 + m];
        }
        out[(size_t)m * OUT_DIM + o] = scale[o] * (s - (float)zp[o] * rsum) + bias[o];
    }
}

extern "C" void kernel_launch(void* const* d_in, const int* in_sizes, int n_in,
                              void* d_out, int out_size, void* d_ws, size_t ws_size,
                              hipStream_t stream) {
    const float* in    = (const float*)d_in[0];
    const int*   wq    = (const int*)d_in[1];   // int8 sign-extended to int32 by harness
    const int*   zp    = (const int*)d_in[2];
    const float* scale = (const float*)d_in[3];
    const float* bias  = (const float*)d_in[4];
    float* out = (float*)d_out;

    gemm_kernel<<<OUT_DIM / 32, 512, 0, stream>>>(in, wq, zp, scale, bias, out);
}

// Round 9
// 366.287 us; speedup vs baseline: 1.1316x; 1.1316x over previous
//
#include <hip/hip_runtime.h>
#include <stdint.h>

#define TOKENS 32
#define IN_DIM 8192
#define OUT_DIM 8192
#define SLABS 4
#define KSLAB (IN_DIM / SLABS)        // 2048 k per block
#define NWAVE 2                       // waves per block (K-split within slab)
#define KRANGE (KSLAB / NWAVE)        // 1024 k per wave
#define BK 128                        // int32 elements per chunk
#define NCHUNK (KRANGE / BK)          // 8 chunks (even)
#define NTILE (OUT_DIM / 32)          // 256 row-tiles

typedef __bf16 bf16x8 __attribute__((ext_vector_type(8)));
typedef float f32x16 __attribute__((ext_vector_type(16)));

static __device__ __forceinline__ uint32_t pk_bf16_2(float f0, float f1) {
    return __builtin_amdgcn_perm(__float_as_uint(f1), __float_as_uint(f0), 0x07060302u);
}
static __device__ __forceinline__ float trunc_bf(float f) {
    return __uint_as_float(__float_as_uint(f) & 0xffff0000u);
}

// ---------- prep: A fp32 -> bf16 (truncate) + per-token rowsum of truncated A ----------
__global__ __launch_bounds__(256) void prep_kernel(const float* __restrict__ in,
                                                   uint16_t* __restrict__ abf,
                                                   float* __restrict__ rowsum) {
    const int t = blockIdx.x;
    const int tid = threadIdx.x;
    const float4* __restrict__ row = reinterpret_cast<const float4*>(in + (size_t)t * IN_DIM);
    ushort4* __restrict__ orow = reinterpret_cast<ushort4*>(abf + (size_t)t * IN_DIM);
    float s = 0.f;
#pragma unroll
    for (int it = 0; it < IN_DIM / 4 / 256; ++it) {     // 8 iters
        const int i4 = it * 256 + tid;
        float4 v = row[i4];
        s += trunc_bf(v.x) + trunc_bf(v.y) + trunc_bf(v.z) + trunc_bf(v.w);
        ushort4 b;
        b.x = (uint16_t)(__float_as_uint(v.x) >> 16);
        b.y = (uint16_t)(__float_as_uint(v.y) >> 16);
        b.z = (uint16_t)(__float_as_uint(v.z) >> 16);
        b.w = (uint16_t)(__float_as_uint(v.w) >> 16);
        orow[i4] = b;
    }
#pragma unroll
    for (int off = 32; off > 0; off >>= 1) s += __shfl_down(s, off);
    __shared__ float wred[4];
    if ((tid & 63) == 0) wred[tid >> 6] = s;
    __syncthreads();
    if (tid == 0) rowsum[t] = wred[0] + wred[1] + wred[2] + wred[3];
}

// ---------- gemm: 1024 blocks = 256 row-tiles x 4 K-slabs; raw f32 partials to ws ----------
__global__ __launch_bounds__(128, 1) void gemm_kernel(
        const uint16_t* __restrict__ abf,
        const int* __restrict__ w,
        float* __restrict__ parts) {
    // per-wave private double buffer: [wave][buf][row][BK] int32 = 64 KB
    __shared__ int lds[NWAVE][2][32][BK];

    const int tid   = threadIdx.x;
    const int wv    = tid >> 6;
    const int lane  = tid & 63;
    const int lo    = lane & 31;      // A-token row / W output row
    const int hi    = lane >> 5;      // k sub-chunk
    const int slab  = blockIdx.x & (SLABS - 1);
    const int tile  = blockIdx.x >> 2;
    const int obase = tile * 32;
    const int k0    = slab * KSLAB + wv * KRANGE;

    // Swizzle: LDS[r][d] = W[obase+r][chunk + (d ^ ((r&7)<<2))] (dwords); XOR is
    // applied to the per-lane GLOBAL source (gll writes LDS linearly).
    auto stage = [&](int c, int b) {
#pragma unroll
        for (int p = 0; p < 16; ++p) {
            const int r   = p * 2 + hi;
            const int swr = (r & 7) << 2;
            const int* g = w + (size_t)(obase + r) * IN_DIM + k0 + c * BK
                             + (((lane & 31) * 4) ^ swr);
            __builtin_amdgcn_global_load_lds(
                (const __attribute__((address_space(1))) void*)g,
                (__attribute__((address_space(3))) void*)&lds[wv][b][p * 2][0],
                16, 0, 0);
        }
    };

    // A: prepacked bf16; lane fragment = abf[lo][k + hi*8 .. +8] (16B)
    const uint16_t* ain = abf + (size_t)lo * IN_DIM + k0 + hi * 8;
    auto aload = [&](int c, uint4 (&ab)[8]) {
#pragma unroll
        for (int s = 0; s < 8; ++s)
            ab[s] = *reinterpret_cast<const uint4*>(ain + c * BK + s * 16);
    };

    f32x16 acc;
#pragma unroll
    for (int i = 0; i < 16; ++i) acc[i] = 0.f;

    const int sw = (lo & 7) << 2;
    const int* lrow0 = &lds[wv][0][lo][0];
    const int* lrow1 = &lds[wv][1][lo][0];

    auto compute = [&](const int* lrow, const uint4 (&ab)[8]) {
#pragma unroll
        for (int s = 0; s < 8; ++s) {
            const int d0 = s * 16 + hi * 8;
            int4 b0 = *reinterpret_cast<const int4*>(lrow + (d0 ^ sw));
            int4 b1 = *reinterpret_cast<const int4*>(lrow + ((d0 + 4) ^ sw));
            union { uint4 u; bf16x8 v; } af;
            af.u = ab[s];
            union { uint32_t u[4]; bf16x8 v; } bf_;
            bf_.u[0] = pk_bf16_2((float)b0.x, (float)b0.y);
            bf_.u[1] = pk_bf16_2((float)b0.z, (float)b0.w);
            bf_.u[2] = pk_bf16_2((float)b1.x, (float)b1.y);
            bf_.u[3] = pk_bf16_2((float)b1.z, (float)b1.w);
            acc = __builtin_amdgcn_mfma_f32_32x32x16_bf16(af.v, bf_.v, acc, 0, 0, 0);
        }
    };

    uint4 ab0[8], ab1[8];

    // Queue order per chunk: [gll x16, A x8]; vmcnt(24) at top of compute(c)
    // retires exactly chunk c's 24 ops; chunk c+1's 24 stay in flight.
    stage(0, 0);
    aload(0, ab0);
    for (int cc = 0; cc < NCHUNK; cc += 2) {
        stage(cc + 1, 1);
        aload(cc + 1, ab1);
        asm volatile("s_waitcnt vmcnt(24)" ::: "memory");
        compute(lrow0, ab0);

        if (cc + 2 < NCHUNK) {
            stage(cc + 2, 0);
            aload(cc + 2, ab0);
            asm volatile("s_waitcnt vmcnt(24)" ::: "memory");
        } else {
            asm volatile("s_waitcnt vmcnt(0)" ::: "memory");
        }
        compute(lrow1, ab1);
    }

    // ---- 2-wave reduce (overlay LDS) + raw partial-tile store ----
    __syncthreads();
    float* red = (float*)&lds[0][0][0][0];              // [NWAVE][1024]
#pragma unroll
    for (int r = 0; r < 16; ++r) {
        const int m = (r & 3) + 8 * (r >> 2) + 4 * hi;  // token (validated layout)
        red[wv * (TOKENS * 32) + m * 32 + lo] = acc[r];
    }
    __syncthreads();

    float* pt = parts + (size_t)(slab * NTILE + tile) * (TOKENS * 32);
    for (int idx = tid; idx < TOKENS * 32; idx += 128)
        pt[idx] = red[idx] + red[TOKENS * 32 + idx];
}

// ---------- reduce: sum 4 slab partials + fused zp/scale/bias epilogue ----------
__global__ __launch_bounds__(256) void reduce_kernel(
        const float* __restrict__ parts,
        const float* __restrict__ rowsum,
        const int* __restrict__ zp,
        const float* __restrict__ scale,
        const float* __restrict__ bias,
        float* __restrict__ out) {
    const int tile = blockIdx.x;
    const int idx  = threadIdx.x * 4;                   // 4 outputs per thread
    const int m    = idx >> 5;                          // token
    const int n    = idx & 31;
    const int o    = tile * 32 + n;

    float4 s = make_float4(0.f, 0.f, 0.f, 0.f);
#pragma unroll
    for (int sl = 0; sl < SLABS; ++sl) {
        float4 p = *reinterpret_cast<const float4*>(
            parts + (size_t)(sl * NTILE + tile) * (TOKENS * 32) + idx);
        s.x += p.x; s.y += p.y; s.z += p.z; s.w += p.w;
    }
    const float rs = rowsum[m];
    const float4 sc = *reinterpret_cast<const float4*>(scale + o);
    const float4 bi = *reinterpret_cast<const float4*>(bias + o);
    const int4   zv = *reinterpret_cast<const int4*>(zp + o);
    float4 r;
    r.x = sc.x * (s.x - (float)zv.x * rs) + bi.x;
    r.y = sc.y * (s.y - (float)zv.y * rs) + bi.y;
    r.z = sc.z * (s.z - (float)zv.z * rs) + bi.z;
    r.w = sc.w * (s.w - (float)zv.w * rs) + bi.w;
    *reinterpret_cast<float4*>(out + (size_t)m * OUT_DIM + o) = r;
}

extern "C" void kernel_launch(void* const* d_in, const int* in_sizes, int n_in,
                              void* d_out, int out_size, void* d_ws, size_t ws_size,
                              hipStream_t stream) {
    const float* in    = (const float*)d_in[0];
    const int*   wq    = (const int*)d_in[1];   // int8 sign-extended to int32 by harness
    const int*   zp    = (const int*)d_in[2];
    const float* scale = (const float*)d_in[3];
    const float* bias  = (const float*)d_in[4];
    float* out = (float*)d_out;

    uint16_t* abf    = (uint16_t*)d_ws;                                  // 512 KB
    float*    rowsum = (float*)((char*)d_ws + (512u << 10));             // 128 B
    float*    parts  = (float*)((char*)d_ws + (1u << 20));               // 4 MB

    prep_kernel<<<TOKENS, 256, 0, stream>>>(in, abf, rowsum);
    gemm_kernel<<<SLABS * NTILE, 128, 0, stream>>>(abf, wq, parts);
    reduce_kernel<<<NTILE, 256, 0, stream>>>(parts, rowsum, zp, scale, bias, out);
}

// Round 11
// 364.754 us; speedup vs baseline: 1.1363x; 1.0042x over previous
//
#include <hip/hip_runtime.h>
#include <stdint.h>

#define TOKENS 32
#define IN_DIM 8192
#define OUT_DIM 8192
#define SLABS 4
#define KSLAB (IN_DIM / SLABS)        // 2048 dwords of k per block
#define BK 256                        // dwords per chunk: 1 KB contiguous per row
#define NCHUNK (KSLAB / BK)           // 8 chunks (even)
#define NTILE (OUT_DIM / 32)          // 256 row-tiles

typedef __bf16 bf16x8 __attribute__((ext_vector_type(8)));
typedef float f32x16 __attribute__((ext_vector_type(16)));

static __device__ __forceinline__ uint32_t pk_bf16_2(float f0, float f1) {
    return __builtin_amdgcn_perm(__float_as_uint(f1), __float_as_uint(f0), 0x07060302u);
}
static __device__ __forceinline__ float trunc_bf(float f) {
    return __uint_as_float(__float_as_uint(f) & 0xffff0000u);
}

// ---------- prep: A fp32 -> bf16 (truncate) + per-token rowsum of truncated A ----------
__global__ __launch_bounds__(256) void prep_kernel(const float* __restrict__ in,
                                                   uint16_t* __restrict__ abf,
                                                   float* __restrict__ rowsum) {
    const int t = blockIdx.x;
    const int tid = threadIdx.x;
    const float4* __restrict__ row = reinterpret_cast<const float4*>(in + (size_t)t * IN_DIM);
    ushort4* __restrict__ orow = reinterpret_cast<ushort4*>(abf + (size_t)t * IN_DIM);
    float s = 0.f;
#pragma unroll
    for (int it = 0; it < IN_DIM / 4 / 256; ++it) {
        const int i4 = it * 256 + tid;
        float4 v = row[i4];
        s += trunc_bf(v.x) + trunc_bf(v.y) + trunc_bf(v.z) + trunc_bf(v.w);
        ushort4 b;
        b.x = (uint16_t)(__float_as_uint(v.x) >> 16);
        b.y = (uint16_t)(__float_as_uint(v.y) >> 16);
        b.z = (uint16_t)(__float_as_uint(v.z) >> 16);
        b.w = (uint16_t)(__float_as_uint(v.w) >> 16);
        orow[i4] = b;
    }
#pragma unroll
    for (int off = 32; off > 0; off >>= 1) s += __shfl_down(s, off);
    __shared__ float wred[4];
    if ((tid & 63) == 0) wred[tid >> 6] = s;
    __syncthreads();
    if (tid == 0) rowsum[t] = wred[0] + wred[1] + wred[2] + wred[3];
}

// ---------- gemm: 1024 blocks (256 tiles x 4 slabs), ONE wave per block ----------
// Each chunk: 32 gll, each a fully-contiguous 1 KB run from one W row; per-block
// XOR phase de-correlates the chunk order across blocks so concurrent reads
// cover all 1KB-offsets of the 32KB row period (DRAM channel spread).
__global__ __launch_bounds__(64, 1) void gemm_kernel(
        const uint16_t* __restrict__ abf,
        const int* __restrict__ w,
        float* __restrict__ parts) {
    __shared__ int lds[2][32][BK];    // double buffer: 2 x 32 KB

    const int lane  = threadIdx.x;    // 0..63
    const int lo    = lane & 31;      // A-token row / W output row
    const int hi    = lane >> 5;      // k sub-chunk
    const int slab  = blockIdx.x & (SLABS - 1);
    const int tile  = blockIdx.x >> 2;
    const int obase = tile * 32;
    const int k0    = slab * KSLAB;   // dword base within row

    const uint32_t phase = (blockIdx.x * 2654435761u) >> 29;   // 0..7

    // Swizzle: LDS[r][d] = W[obase+r][k0 + c*BK + (d ^ ((r&7)<<2))] (dwords);
    // XOR applied to the per-lane GLOBAL source (gll writes LDS linearly).
    auto stage = [&](int c, int b) {
#pragma unroll
        for (int p = 0; p < 32; ++p) {
            const int swr = (p & 7) << 2;
            const int* g = w + (size_t)(obase + p) * IN_DIM + k0 + c * BK
                             + ((lane * 4) ^ swr);
            __builtin_amdgcn_global_load_lds(
                (const __attribute__((address_space(1))) void*)g,
                (__attribute__((address_space(3))) void*)&lds[b][p][0],
                16, 0, 0);
        }
    };

    // A: prepacked bf16; per k-step s the lane needs abf[lo][k + s*16 + hi*8 ..+8]
    const uint16_t* ain = abf + (size_t)lo * IN_DIM + k0 + hi * 8;
    auto aload = [&](int c, uint4 (&ab)[16]) {
#pragma unroll
        for (int s = 0; s < 16; ++s)
            ab[s] = *reinterpret_cast<const uint4*>(ain + c * BK + s * 16);
    };

    f32x16 acc;
#pragma unroll
    for (int i = 0; i < 16; ++i) acc[i] = 0.f;

    const int sw = (lo & 7) << 2;
    const int* lrow0 = &lds[0][lo][0];
    const int* lrow1 = &lds[1][lo][0];

    auto compute = [&](const int* lrow, const uint4 (&ab)[16]) {
#pragma unroll
        for (int s = 0; s < 16; ++s) {
            const int d0 = s * 16 + hi * 8;
            int4 b0 = *reinterpret_cast<const int4*>(lrow + (d0 ^ sw));
            int4 b1 = *reinterpret_cast<const int4*>(lrow + ((d0 + 4) ^ sw));
            union { uint4 u; bf16x8 v; } af;
            af.u = ab[s];
            union { uint32_t u[4]; bf16x8 v; } bf_;
            bf_.u[0] = pk_bf16_2((float)b0.x, (float)b0.y);
            bf_.u[1] = pk_bf16_2((float)b0.z, (float)b0.w);
            bf_.u[2] = pk_bf16_2((float)b1.x, (float)b1.y);
            bf_.u[3] = pk_bf16_2((float)b1.z, (float)b1.w);
            acc = __builtin_amdgcn_mfma_f32_32x32x16_bf16(af.v, bf_.v, acc, 0, 0, 0);
        }
    };

    uint4 ab0[16], ab1[16];

    // Queue per chunk: [gll x32, A x16] = 48 ops; vmcnt(48) at top of compute(c)
    // retires exactly chunk c's ops while chunk c+1's 48 stay in flight.
    stage(phase ^ 0, 0);
    aload(phase ^ 0, ab0);
    for (int ci = 0; ci < NCHUNK; ci += 2) {
        stage(phase ^ (ci + 1), 1);
        aload(phase ^ (ci + 1), ab1);
        asm volatile("s_waitcnt vmcnt(48)" ::: "memory");
        compute(lrow0, ab0);

        if (ci + 2 < NCHUNK) {
            stage(phase ^ (ci + 2), 0);
            aload(phase ^ (ci + 2), ab0);
            asm volatile("s_waitcnt vmcnt(48)" ::: "memory");
        } else {
            asm volatile("s_waitcnt vmcnt(0)" ::: "memory");
        }
        compute(lrow1, ab1);
    }

    // ---- store raw 32x32 partial tile straight from acc (no LDS, no barrier) ----
    float* pt = parts + (size_t)(slab * NTILE + tile) * (TOKENS * 32);
#pragma unroll
    for (int r = 0; r < 16; ++r) {
        const int m = (r & 3) + 8 * (r >> 2) + 4 * hi;  // token (validated layout)
        pt[m * 32 + lo] = acc[r];
    }
}

// ---------- reduce: sum 4 slab partials + fused zp/scale/bias epilogue ----------
__global__ __launch_bounds__(256) void reduce_kernel(
        const float* __restrict__ parts,
        const float* __restrict__ rowsum,
        const int* __restrict__ zp,
        const float* __restrict__ scale,
        const float* __restrict__ bias,
        float* __restrict__ out) {
    const int tile = blockIdx.x;
    const int idx  = threadIdx.x * 4;
    const int m    = idx >> 5;
    const int n    = idx & 31;
    const int o    = tile * 32 + n;

    float4 s = make_float4(0.f, 0.f, 0.f, 0.f);
#pragma unroll
    for (int sl = 0; sl < SLABS; ++sl) {
        float4 p = *reinterpret_cast<const float4*>(
            parts + (size_t)(sl * NTILE + tile) * (TOKENS * 32) + idx);
        s.x += p.x; s.y += p.y; s.z += p.z; s.w += p.w;
    }
    const float rs = rowsum[m];
    const float4 sc = *reinterpret_cast<const float4*>(scale + o);
    const float4 bi = *reinterpret_cast<const float4*>(bias + o);
    const int4   zv = *reinterpret_cast<const int4*>(zp + o);
    float4 r;
    r.x = sc.x * (s.x - (float)zv.x * rs) + bi.x;
    r.y = sc.y * (s.y - (float)zv.y * rs) + bi.y;
    r.z = sc.z * (s.z - (float)zv.z * rs) + bi.z;
    r.w = sc.w * (s.w - (float)zv.w * rs) + bi.w;
    *reinterpret_cast<float4*>(out + (size_t)m * OUT_DIM + o) = r;
}

extern "C" void kernel_launch(void* const* d_in, const int* in_sizes, int n_in,
                              void* d_out, int out_size, void* d_ws, size_t ws_size,
                              hipStream_t stream) {
    const float* in    = (const float*)d_in[0];
    const int*   wq    = (const int*)d_in[1];   // int8 sign-extended to int32 by harness
    const int*   zp    = (const int*)d_in[2];
    const float* scale = (const float*)d_in[3];
    const float* bias  = (const float*)d_in[4];
    float* out = (float*)d_out;

    uint16_t* abf    = (uint16_t*)d_ws;                                  // 512 KB
    float*    rowsum = (float*)((char*)d_ws + (512u << 10));             // 128 B
    float*    parts  = (float*)((char*)d_ws + (1u << 20));               // 4 MB

    prep_kernel<<<TOKENS, 256, 0, stream>>>(in, abf, rowsum);
    gemm_kernel<<<NTILE * SLABS, 64, 0, stream>>>(abf, wq, parts);
    reduce_kernel<<<NTILE, 256, 0, stream>>>(parts, rowsum, zp, scale, bias, out);
}